// Round 12
// baseline (51.937 us; speedup 1.0000x reference)
//
#include <hip/hip_runtime.h>

// SelfAttentionHead: B=16, T=1024, C=768, H=64, fp32 in/out, causal softmax.
// wtrans: W -> Wt[192][768] f16.
// proj:   R9 register-staged LDS GEMM, prefetch depth 2 (~7-9 us, HBM floor).
// attn:   block-cooperative split-KV flash, CHUNK=2 KV tiles (was 4), heavy-
//         first job order, defer-max (THR=4, log2), setprio on MFMA clusters,
//         f16 partials. LSE-combine merges <=8 chunks.

typedef _Float16 half8 __attribute__((ext_vector_type(8)));
typedef _Float16 half4 __attribute__((ext_vector_type(4)));
typedef float float4v __attribute__((ext_vector_type(4)));

#define NB   16
#define NT   1024
#define NC   768
#define NH   64

typedef __attribute__((address_space(3))) unsigned int lds_u32_t;
typedef const __attribute__((address_space(1))) unsigned int g_u32_t;

__device__ __forceinline__ void gload16(const void* g, void* l) {
    __builtin_amdgcn_global_load_lds((g_u32_t*)g, (lds_u32_t*)l, 16, 0, 0);
}

// ---------------------------------------------------------------------------
// Wt[m*64+col][k] = Wm[k][col]. Grid (48,3) x 256.
// ---------------------------------------------------------------------------
__global__ __launch_bounds__(256) void wtrans_kernel(
    const float* __restrict__ Wq, const float* __restrict__ Wk,
    const float* __restrict__ Wv, _Float16* __restrict__ Wt)
{
    __shared__ float tile[16][68];
    const int m = blockIdx.y;
    const float* W = (m == 0) ? Wq : (m == 1) ? Wk : Wv;
    const int s = blockIdx.x;
    const int t = threadIdx.x;
    {
        const int kr = t >> 4, c4 = (t & 15) * 4;
        float4v v = *(const float4v*)(W + (size_t)(s * 16 + kr) * NH + c4);
        tile[kr][c4 + 0] = v[0]; tile[kr][c4 + 1] = v[1];
        tile[kr][c4 + 2] = v[2]; tile[kr][c4 + 3] = v[3];
    }
    __syncthreads();
    const int col = t >> 2, j = t & 3;
    half4 h;
#pragma unroll
    for (int i = 0; i < 4; ++i) h[i] = (_Float16)tile[j * 4 + i][col];
    *(half4*)(Wt + (size_t)(m * 64 + col) * NC + s * 16 + j * 4) = h;
}

// ---------------------------------------------------------------------------
// proj: grid 512 x 256 thr. Block: 32 rows x 192 cols, BK=64, depth-2 prefetch.
// (unchanged — measured near HBM floor)
// ---------------------------------------------------------------------------
__global__ __launch_bounds__(256) void proj_kernel(
    const float* __restrict__ x, const _Float16* __restrict__ Wt,
    _Float16* __restrict__ Qb, _Float16* __restrict__ Kb,
    _Float16* __restrict__ Vt)
{
    __shared__ _Float16 xl[32][68];

    const int t   = threadIdx.x;
    const int wid = t >> 6, lane = t & 63;
    const int l15 = lane & 15, lhi = lane >> 4;
    const int m0  = blockIdx.x * 32;
    const int srow = t >> 3, sc0 = (t & 7) * 8;

    const float*    xsrc  = x  + (size_t)(m0 + srow) * NC + sc0;
    const _Float16* wbase = Wt + (size_t)(wid * 48 + l15) * NC + lhi * 8;

    float4v acc[2][3];
#pragma unroll
    for (int i = 0; i < 2; ++i)
#pragma unroll
        for (int j = 0; j < 3; ++j)
            acc[i][j] = (float4v){0.f, 0.f, 0.f, 0.f};

    float4v g0[2], g1[2];
    half8 bf[2][3][2];
#pragma unroll
    for (int p = 0; p < 2; ++p) {
        g0[p] = *(const float4v*)(xsrc + p * 64);
        g1[p] = *(const float4v*)(xsrc + p * 64 + 4);
#pragma unroll
        for (int nf = 0; nf < 3; ++nf)
#pragma unroll
            for (int ks = 0; ks < 2; ++ks)
                bf[p][nf][ks] = *(const half8*)(wbase + (size_t)nf * 16 * NC
                                                + p * 64 + ks * 32);
    }

#pragma unroll 2
    for (int kc = 0; kc < 12; ++kc) {
        const int cur = kc & 1;
        __syncthreads();
        {
            half8 h;
            h[0] = (_Float16)g0[cur][0]; h[1] = (_Float16)g0[cur][1];
            h[2] = (_Float16)g0[cur][2]; h[3] = (_Float16)g0[cur][3];
            h[4] = (_Float16)g1[cur][0]; h[5] = (_Float16)g1[cur][1];
            h[6] = (_Float16)g1[cur][2]; h[7] = (_Float16)g1[cur][3];
            *(half8*)&xl[srow][sc0] = h;
        }
        __syncthreads();

        half8 bcur[3][2];
#pragma unroll
        for (int nf = 0; nf < 3; ++nf)
#pragma unroll
            for (int ks = 0; ks < 2; ++ks) bcur[nf][ks] = bf[cur][nf][ks];

        if (kc + 2 < 12) {
            g0[cur] = *(const float4v*)(xsrc + (kc + 2) * 64);
            g1[cur] = *(const float4v*)(xsrc + (kc + 2) * 64 + 4);
#pragma unroll
            for (int nf = 0; nf < 3; ++nf)
#pragma unroll
                for (int ks = 0; ks < 2; ++ks)
                    bf[cur][nf][ks] = *(const half8*)(wbase + (size_t)nf * 16 * NC
                                                      + (kc + 2) * 64 + ks * 32);
        }

        half8 af[2][2];
#pragma unroll
        for (int mf = 0; mf < 2; ++mf)
#pragma unroll
            for (int ks = 0; ks < 2; ++ks)
                af[mf][ks] = *(const half8*)&xl[mf * 16 + l15][ks * 32 + lhi * 8];

#pragma unroll
        for (int ks = 0; ks < 2; ++ks)
#pragma unroll
            for (int mf = 0; mf < 2; ++mf)
#pragma unroll
                for (int nf = 0; nf < 3; ++nf)
                    acc[mf][nf] = __builtin_amdgcn_mfma_f32_16x16x32_f16(
                        af[mf][ks], bcur[nf][ks], acc[mf][nf], 0, 0, 0);
    }

#pragma unroll
    for (int nf = 0; nf < 3; ++nf) {
        const int gc  = wid * 48 + nf * 16;
        const int sel = gc >> 6;
        const int col = (gc & 63) + l15;
#pragma unroll
        for (int mf = 0; mf < 2; ++mf) {
            const int row0 = m0 + mf * 16 + lhi * 4;
            if (sel == 2) {
                const int bb = row0 >> 10, tt = row0 & 1023;
                half4 h;
#pragma unroll
                for (int r = 0; r < 4; ++r) h[r] = (_Float16)acc[mf][nf][r];
                *(half4*)(Vt + ((size_t)(bb * 64 + col)) * NT + tt) = h;
            } else {
                _Float16* D = (sel == 0) ? Qb : Kb;
#pragma unroll
                for (int r = 0; r < 4; ++r)
                    D[(size_t)(row0 + r) * NH + col] = (_Float16)acc[mf][nf][r];
            }
        }
    }
}

// ---------------------------------------------------------------------------
// attn partial: grid (72, 16) x 256 thr (4 waves). Job i = 71-bx (heavy
// first) -> (qi, c) via cumsum table; chunk = KV tiles [2c, min(2c+2, qi+1)).
// K/V staged to shared LDS (double buffer, swizzled global_load_lds).
// Defer-max THR=4 (log2), setprio MFMA clusters, f16 partials.
// qw = qi*4+w, 8 chunk slots per qw.
// ---------------------------------------------------------------------------
__global__ __launch_bounds__(256) void attn_part_kernel(
    const _Float16* __restrict__ Qb, const _Float16* __restrict__ Kb,
    const _Float16* __restrict__ Vt, _Float16* __restrict__ partO,
    float* __restrict__ partML)
{
    __shared__ _Float16 Kl[2][64 * 64];
    __shared__ _Float16 Vl[2][64 * 64];

    const int tid = threadIdx.x;
    const int lane = tid & 63, w = tid >> 6;
    const int l15 = lane & 15, lhi = lane >> 4;
    const int b = blockIdx.y;
    const int i = 71 - blockIdx.x;     // heavy jobs first

    // job -> (qi, c): starts = cumsum of ceil((qi+1)/2)
    int qi = 0, st = 0;
    {
        const int starts[16] = {0,1,2,4,6,9,12,16,20,25,30,36,42,49,56,64};
#pragma unroll
        for (int k = 1; k < 16; ++k)
            if (i >= starts[k]) { qi = k; st = starts[k]; }
    }
    const int c  = i - st;
    const int nt = qi + 1;
    const int t0 = c * 2;
    const int t1 = min(t0 + 2, nt);
    const int q0 = qi * 64;
    const int qrel = w * 16 + l15;     // q within 64-row tile (for mask)

    const _Float16* qsrc = Qb + ((size_t)(b * NT + q0 + w * 16 + l15)) * NH + lhi * 8;
    const half8 aq0 = *(const half8*)qsrc;
    const half8 aq1 = *(const half8*)(qsrc + 32);

    // staging: slot s in [0,512): row = s>>3, chunk = (s&7) ^ (row&7)
    const int s1 = w * 64 + lane, s2 = 256 + w * 64 + lane;
    const int r1 = s1 >> 3, c1 = (s1 & 7) ^ (r1 & 7);
    const int r2 = s2 >> 3, c2 = (s2 & 7) ^ (r2 & 7);
    const _Float16* ksrc1 = Kb + ((size_t)(b * NT + r1)) * NH + c1 * 8;
    const _Float16* ksrc2 = Kb + ((size_t)(b * NT + r2)) * NH + c2 * 8;
    const _Float16* vsrc1 = Vt + ((size_t)(b * 64 + r1)) * NT + c1 * 8;
    const _Float16* vsrc2 = Vt + ((size_t)(b * 64 + r2)) * NT + c2 * 8;

    auto STAGE = [&](int jt, int buf) {
        gload16(ksrc1 + (size_t)jt * 64 * NH, &Kl[buf][(size_t)(w * 64) * 8]);
        gload16(ksrc2 + (size_t)jt * 64 * NH, &Kl[buf][(size_t)(256 + w * 64) * 8]);
        gload16(vsrc1 + jt * 64, &Vl[buf][(size_t)(w * 64) * 8]);
        gload16(vsrc2 + jt * 64, &Vl[buf][(size_t)(256 + w * 64) * 8]);
    };

    float4v o[4];
#pragma unroll
    for (int nf = 0; nf < 4; ++nf) o[nf] = (float4v){0.f, 0.f, 0.f, 0.f};
    float m2 = -1e30f, lsum = 0.f;

    STAGE(t0, 0);
    asm volatile("s_waitcnt vmcnt(0)" ::: "memory");
    __syncthreads();

    for (int jt = t0; jt < t1; ++jt) {
        const int buf = (jt - t0) & 1;
        const bool last = (jt == nt - 1);
        if (jt + 1 < t1) STAGE(jt + 1, buf ^ 1);

        // S^T = K * Q^T from LDS
        float4v sT[4];
        __builtin_amdgcn_s_setprio(1);
#pragma unroll
        for (int kf = 0; kf < 4; ++kf) {
            const int row = kf * 16 + l15;
            const int sw = row & 7;
            half8 bk0 = *(const half8*)&Kl[buf][row * 64 + ((lhi     ^ sw) * 8)];
            half8 bk1 = *(const half8*)&Kl[buf][row * 64 + (((4+lhi) ^ sw) * 8)];
            float4v sv = (float4v){0.f, 0.f, 0.f, 0.f};
            sv = __builtin_amdgcn_mfma_f32_16x16x32_f16(bk0, aq0, sv, 0, 0, 0);
            sv = __builtin_amdgcn_mfma_f32_16x16x32_f16(bk1, aq1, sv, 0, 0, 0);
            sT[kf] = sv;
        }
        __builtin_amdgcn_s_setprio(0);

        const float SC = 0.18033688f;   // 0.125 * log2(e)
        float p[4][4];
        float mt = -1e30f;
#pragma unroll
        for (int kf = 0; kf < 4; ++kf)
#pragma unroll
            for (int r = 0; r < 4; ++r) {
                float v = sT[kf][r] * SC;
                if (last) {
                    const int kpos = kf * 16 + lhi * 4 + r;
                    if (kpos > qrel) v = -1e30f;
                }
                p[kf][r] = v;
                mt = fmaxf(mt, v);
            }
        mt = fmaxf(mt, __shfl_xor(mt, 16));
        mt = fmaxf(mt, __shfl_xor(mt, 32));

        // defer-max: only rescale when the tile max grew past THR=4 (log2)
        if (__any(mt - m2 > 4.0f)) {
            const float mnew = fmaxf(m2, mt);
            const float esc  = exp2f(m2 - mnew);
            float er[4];
#pragma unroll
            for (int r = 0; r < 4; ++r) er[r] = __shfl(esc, lhi * 4 + r);
#pragma unroll
            for (int nf = 0; nf < 4; ++nf)
#pragma unroll
                for (int r = 0; r < 4; ++r) o[nf][r] *= er[r];
            lsum *= esc;
            m2 = mnew;
        }

        float ps = 0.f;
#pragma unroll
        for (int kf = 0; kf < 4; ++kf)
#pragma unroll
            for (int r = 0; r < 4; ++r) {
                const float e = exp2f(p[kf][r] - m2);   // bounded by 2^4
                p[kf][r] = e;
                ps += e;
            }
        ps += __shfl_xor(ps, 16);
        ps += __shfl_xor(ps, 32);
        lsum += ps;

        unsigned int pk[4][2];
#pragma unroll
        for (int kf = 0; kf < 4; ++kf)
#pragma unroll
            for (int pr = 0; pr < 2; ++pr) {
                auto h2 = __builtin_amdgcn_cvt_pkrtz(p[kf][2 * pr], p[kf][2 * pr + 1]);
                pk[kf][pr] = __builtin_bit_cast(unsigned int, h2);
            }

        const int sb = l15 + ((lhi & 1) * 2) * 16;
        const bool hi = (lhi >> 1) != 0;
#pragma unroll
        for (int ks = 0; ks < 2; ++ks) {
            unsigned int wv[4];
#pragma unroll
            for (int m = 0; m < 4; ++m) {
                const int L = sb + ((m >> 1) << 4);
                const unsigned int wA = (unsigned int)__shfl((int)pk[2 * ks + 0][m & 1], L);
                const unsigned int wB = (unsigned int)__shfl((int)pk[2 * ks + 1][m & 1], L);
                wv[m] = hi ? wB : wA;
            }
            union { unsigned int u[4]; half8 h; } cvt;
            cvt.u[0] = wv[0]; cvt.u[1] = wv[1]; cvt.u[2] = wv[2]; cvt.u[3] = wv[3];
            const half8 pa = cvt.h;
            __builtin_amdgcn_s_setprio(1);
#pragma unroll
            for (int nf = 0; nf < 4; ++nf) {
                const int row = nf * 16 + l15;
                const half8 bvv = *(const half8*)&Vl[buf][row * 64
                                    + (((ks * 4 + lhi) ^ (row & 7)) * 8)];
                o[nf] = __builtin_amdgcn_mfma_f32_16x16x32_f16(pa, bvv, o[nf], 0, 0, 0);
            }
            __builtin_amdgcn_s_setprio(0);
        }

        asm volatile("s_waitcnt vmcnt(0)" ::: "memory");
        __syncthreads();
    }

    // write partials: O as f16, (m,l) as f32. 8 chunk slots per qw.
    const size_t base = (size_t)((b * 64 + qi * 4 + w) * 8 + c);
#pragma unroll
    for (int nf = 0; nf < 4; ++nf) {
        half4 h;
#pragma unroll
        for (int r = 0; r < 4; ++r) h[r] = (_Float16)o[nf][r];
        *(half4*)(partO + (base * 4 + nf) * 256 + lane * 4) = h;
    }
    if (lhi == 0) {
        partML[base * 32 + l15 * 2 + 0] = m2;
        partML[base * 32 + l15 * 2 + 1] = lsum;
    }
}

// ---------------------------------------------------------------------------
// combine: grid (64, 16) x 64 thr. Two-pass merge of <=8 chunks per q-group.
// ---------------------------------------------------------------------------
__global__ __launch_bounds__(64) void attn_comb_kernel(
    const _Float16* __restrict__ partO, const float* __restrict__ partML,
    float* __restrict__ out)
{
    const int lane = threadIdx.x;
    const int l15 = lane & 15, lhi = lane >> 4;
    const int qw = blockIdx.x, b = blockIdx.y;
    const int nch = ((qw >> 2) + 2) >> 1;        // ceil((qi+1)/2), qi = qw>>2
    const size_t gbase = (size_t)(b * 64 + qw) * 8;

    // pass A: global max per row
    float M[4];
#pragma unroll
    for (int r = 0; r < 4; ++r) M[r] = -1e30f;
#pragma unroll
    for (int cc = 0; cc < 8; ++cc) {
        if (cc < nch) {
#pragma unroll
            for (int r = 0; r < 4; ++r)
                M[r] = fmaxf(M[r], partML[(gbase + cc) * 32 + (lhi * 4 + r) * 2]);
        }
    }

    // pass B: accumulate L and O
    float L[4] = {0.f, 0.f, 0.f, 0.f};
    float acc[4][4];
#pragma unroll
    for (int nf = 0; nf < 4; ++nf)
#pragma unroll
        for (int r = 0; r < 4; ++r) acc[nf][r] = 0.f;

#pragma unroll
    for (int cc = 0; cc < 8; ++cc) {
        if (cc < nch) {
            float sc[4];
#pragma unroll
            for (int r = 0; r < 4; ++r) {
                const float mc = partML[(gbase + cc) * 32 + (lhi * 4 + r) * 2 + 0];
                const float lc = partML[(gbase + cc) * 32 + (lhi * 4 + r) * 2 + 1];
                sc[r] = exp2f(mc - M[r]);
                L[r] += lc * sc[r];
            }
#pragma unroll
            for (int nf = 0; nf < 4; ++nf) {
                half4 v = *(const half4*)(partO + ((gbase + cc) * 4 + nf) * 256
                                          + lane * 4);
#pragma unroll
                for (int r = 0; r < 4; ++r) acc[nf][r] += (float)v[r] * sc[r];
            }
        }
    }

#pragma unroll
    for (int nf = 0; nf < 4; ++nf)
#pragma unroll
        for (int r = 0; r < 4; ++r) {
            const int row = qw * 16 + lhi * 4 + r;
            out[((size_t)(b * NT + row)) * NH + nf * 16 + l15]
                = acc[nf][r] / L[r];
        }
}

extern "C" void kernel_launch(void* const* d_in, const int* in_sizes, int n_in,
                              void* d_out, int out_size, void* d_ws, size_t ws_size,
                              hipStream_t stream) {
    const float* x  = (const float*)d_in[0];
    const float* Wk = (const float*)d_in[1];
    const float* Wq = (const float*)d_in[2];
    const float* Wv = (const float*)d_in[3];

    _Float16* Qb = (_Float16*)d_ws;                        // 2 MB
    _Float16* Kb = Qb + (size_t)NB * NT * NH;              // 2 MB
    _Float16* Vt = Kb + (size_t)NB * NT * NH;              // 2 MB (transposed V)
    _Float16* Wt = Vt + (size_t)NB * NT * NH;              // 288 KB
    _Float16* partO  = (_Float16*)((char*)d_ws + (size_t)16 * 1024 * 1024); // 17 MB
    float*    partML = (float*)((char*)d_ws + (size_t)40 * 1024 * 1024);    // 1 MB

    wtrans_kernel<<<dim3(48, 3), dim3(256), 0, stream>>>(Wq, Wk, Wv, Wt);
    proj_kernel<<<dim3(512), dim3(256), 0, stream>>>(x, Wt, Qb, Kb, Vt);
    attn_part_kernel<<<dim3(72, 16), dim3(256), 0, stream>>>(Qb, Kb, Vt, partO, partML);
    attn_comb_kernel<<<dim3(64, 16), dim3(64), 0, stream>>>(partO, partML, (float*)d_out);
}